// Round 1
// baseline (581.825 us; speedup 1.0000x reference)
//
#include <hip/hip_runtime.h>

#define DEV __device__ __forceinline__

using f32x4  = __attribute__((ext_vector_type(4))) float;
using bf16x8 = __attribute__((ext_vector_type(8))) __bf16;
using u16x4  = __attribute__((ext_vector_type(4))) unsigned short;

constexpr int S_ = 2048, D_ = 1024, H_ = 16, DK_ = 64;

DEV unsigned short f2bf(float x) {
  unsigned int u = __float_as_uint(x);
  u += 0x7fffu + ((u >> 16) & 1u);
  return (unsigned short)(u >> 16);
}

DEV void gload_lds16(const void* g, void* l) {
  __builtin_amdgcn_global_load_lds(
      (__attribute__((address_space(1))) void*)g,
      (__attribute__((address_space(3))) void*)l, 16, 0, 0);
}

DEV f32x4 mfma_bf16(bf16x8 a, bf16x8 b, f32x4 c) {
  return __builtin_amdgcn_mfma_f32_16x16x32_bf16(a, b, c, 0, 0, 0);
}

// ---------------- elementwise converters / packers ----------------

__global__ __launch_bounds__(256) void f32_to_bf16_vec(
    const float* __restrict__ s, unsigned short* __restrict__ d, int n4) {
  int i = blockIdx.x * 256 + threadIdx.x;
  if (i >= n4) return;
  f32x4 v = *(const f32x4*)(s + (size_t)i * 4);
  u16x4 o;
  o[0] = f2bf(v[0]); o[1] = f2bf(v[1]); o[2] = f2bf(v[2]); o[3] = f2bf(v[3]);
  *(u16x4*)(d + (size_t)i * 4) = o;
}

// WT[n][d] = W[h][d][kk], n = h*64+kk   (Wq / Wk, total 1024*1024)
__global__ __launch_bounds__(256) void pack_wqk(
    const float* __restrict__ W, unsigned short* __restrict__ WT) {
  int i = blockIdx.x * 256 + threadIdx.x;
  int d = i & 1023, n = i >> 10;
  int hh = n >> 6, kk = n & 63;
  WT[i] = f2bf(W[((size_t)hh * 1024 + d) * 64 + kk]);
}

// WvT[kk][d] = Wv[d][kk]   (64*1024)
__global__ __launch_bounds__(256) void pack_wv(
    const float* __restrict__ W, unsigned short* __restrict__ WT) {
  int i = blockIdx.x * 256 + threadIdx.x;
  int d = i & 1023, kk = i >> 10;
  WT[i] = f2bf(W[(size_t)d * 64 + kk]);
}

// WhT[n][k] = Wh[k][n]   (1024*64)
__global__ __launch_bounds__(256) void pack_wh(
    const float* __restrict__ W, unsigned short* __restrict__ WT) {
  int i = blockIdx.x * 256 + threadIdx.x;
  int k = i & 63, n = i >> 6;
  WT[i] = f2bf(W[(size_t)k * 1024 + n]);
}

__global__ __launch_bounds__(256) void mean_heads(
    const float* __restrict__ heads, unsigned short* __restrict__ hbar) {
  int i = blockIdx.x * 256 + threadIdx.x;  // 4096*64
  int kk = i & 63, m = i >> 6;
  int b = m >> 11, s = m & 2047;
  float acc = 0.f;
#pragma unroll
  for (int hh = 0; hh < 16; ++hh)
    acc += heads[(((size_t)b * 16 + hh) * 2048 + s) * 64 + kk];
  hbar[i] = f2bf(acc * 0.0625f);
}

// ---------------- bf16 MFMA GEMM, C = A * BT^T (+bias), custom epilogues ----
// MODE 0: bf16 out at [b][h][s][kk]  (m=b*2048+s, n=h*64+kk)  (qs/ks)
// MODE 1: bf16 out at [b][n][t]      (m=b*2048+t, N=64)       (vsT)
// MODE 2: f32 out at [m][n]          (out projection, no bias)

template <int BN, int MODE>
__global__ __launch_bounds__(256) void gemm_bt(
    const unsigned short* __restrict__ A, const unsigned short* __restrict__ BT,
    const float* __restrict__ bias, void* __restrict__ outp, int M, int N, int K) {
  constexpr int BM = 128, BK = 64;
  constexpr int NWC = BN / 64;     // waves along N
  constexpr int NWR = 4 / NWC;     // waves along M
  constexpr int WTM = BM / NWR;    // rows per wave
  constexpr int MI = WTM / 16;
  constexpr int NI = 4;
  __shared__ unsigned short ldsA[BM * BK];
  __shared__ unsigned short ldsB[BN * BK];
  const int tid = threadIdx.x;
  const int wave = tid >> 6, lane = tid & 63;
  const int g = lane >> 4, l4 = lane & 15;
  const int m0 = blockIdx.x * BM, n0 = blockIdx.y * BN;
  const int wr = wave / NWC, wc = wave % NWC;
  const int r8 = lane >> 3, s8 = lane & 7;
  f32x4 acc[MI][NI];
#pragma unroll
  for (int mi = 0; mi < MI; ++mi)
#pragma unroll
    for (int ni = 0; ni < NI; ++ni) acc[mi][ni] = {0.f, 0.f, 0.f, 0.f};

  for (int k0 = 0; k0 < K; k0 += BK) {
    __syncthreads();
#pragma unroll
    for (int j = 0; j < 4; ++j) {  // A: 16 chunks of 1 KiB
      int c = wave * 4 + j;
      int row = c * 8 + r8;
      int slot = s8 ^ (row & 7);
      gload_lds16(A + (size_t)(m0 + row) * K + k0 + slot * 8, &ldsA[c * 512]);
    }
    constexpr int BCH = BN * BK / 512;  // 16 or 8 chunks
#pragma unroll
    for (int j = 0; j < BCH / 4; ++j) {
      int c = wave * (BCH / 4) + j;
      int row = c * 8 + r8;
      int slot = s8 ^ (row & 7);
      gload_lds16(BT + (size_t)(n0 + row) * K + k0 + slot * 8, &ldsB[c * 512]);
    }
    __syncthreads();
    bf16x8 af[MI][2], bfr[NI][2];
#pragma unroll
    for (int mi = 0; mi < MI; ++mi)
#pragma unroll
      for (int kss = 0; kss < 2; ++kss) {
        int row = wr * WTM + mi * 16 + l4;
        int slot = (kss * 4 + g) ^ (row & 7);
        af[mi][kss] = *(const bf16x8*)&ldsA[row * 64 + slot * 8];
      }
#pragma unroll
    for (int ni = 0; ni < NI; ++ni)
#pragma unroll
      for (int kss = 0; kss < 2; ++kss) {
        int row = wc * 64 + ni * 16 + l4;
        int slot = (kss * 4 + g) ^ (row & 7);
        bfr[ni][kss] = *(const bf16x8*)&ldsB[row * 64 + slot * 8];
      }
#pragma unroll
    for (int mi = 0; mi < MI; ++mi)
#pragma unroll
      for (int ni = 0; ni < NI; ++ni)
#pragma unroll
        for (int kss = 0; kss < 2; ++kss)
          acc[mi][ni] = mfma_bf16(af[mi][kss], bfr[ni][kss], acc[mi][ni]);
  }

#pragma unroll
  for (int mi = 0; mi < MI; ++mi)
#pragma unroll
    for (int ni = 0; ni < NI; ++ni)
#pragma unroll
      for (int r = 0; r < 4; ++r) {
        int m = m0 + wr * WTM + mi * 16 + g * 4 + r;
        int n = n0 + wc * 64 + ni * 16 + l4;
        float c = acc[mi][ni][r];
        if constexpr (MODE != 2) c += bias[n];
        if constexpr (MODE == 0) {
          int b = m >> 11, s = m & 2047, hh = n >> 6, kk = n & 63;
          ((unsigned short*)outp)[(((size_t)b * 16 + hh) * 2048 + s) * 64 + kk] = f2bf(c);
        } else if constexpr (MODE == 1) {
          int b = m >> 11, t = m & 2047;
          ((unsigned short*)outp)[((size_t)b * 64 + n) * 2048 + t] = f2bf(c);
        } else {
          ((float*)outp)[(size_t)m * N + n] = c;
        }
      }
}

// ---------------- fused attention ----------------
// block = (b,h, 64 q-rows); 4 waves x 16 rows. Two passes over T:
// pass1: scores -> blended -> online (max,sum); pass2: recompute, write attn,
// PV-accumulate (V pre-transposed: vsT[b][kk][t]).

__global__ __launch_bounds__(256) void attn_kernel(
    const unsigned short* __restrict__ qs, const unsigned short* __restrict__ ks,
    const unsigned short* __restrict__ vsT, const int* __restrict__ mask,
    const float* __restrict__ prior, float* __restrict__ attn_out,
    float* __restrict__ heads) {
  __shared__ unsigned short lds_q[64 * 64];
  __shared__ unsigned short lds_k[64 * 64];
  __shared__ unsigned short lds_v[64 * 64];
  __shared__ unsigned short lds_p[4][16 * 64];

  const int tid = threadIdx.x;
  const int wave = tid >> 6, lane = tid & 63;
  const int g = lane >> 4, l4 = lane & 15;
  const int blk = blockIdx.x;
  const int sblk = blk & 31, bh = blk >> 5;
  const int b = bh >> 4, h = bh & 15;

  const size_t bhS = (size_t)bh * S_;
  const unsigned short* qsb = qs + (bhS + sblk * 64) * DK_;
  const unsigned short* ksb = ks + bhS * DK_;
  const unsigned short* vtb = vsT + (size_t)b * DK_ * S_;
  const size_t srow0 = (size_t)b * S_ + sblk * 64;
  const int* maskb = mask + srow0 * S_;
  const float* prib = prior + srow0 * S_;
  float* attb = attn_out + (srow0 * H_ + h) * S_;
  float* headb = heads + (bhS + sblk * 64) * DK_;

  const int r8 = lane >> 3, s8 = lane & 7;

  // stage Q tile once (swizzled), keep A-frags in registers
#pragma unroll
  for (int j = 0; j < 2; ++j) {
    int c = wave * 2 + j;
    int row = c * 8 + r8;
    int slot = s8 ^ (row & 7);
    gload_lds16(qsb + (size_t)row * 64 + slot * 8, &lds_q[c * 512]);
  }
  __syncthreads();
  bf16x8 aq[2];
  {
    int row = wave * 16 + l4;
#pragma unroll
    for (int kss = 0; kss < 2; ++kss) {
      int slot = (kss * 4 + g) ^ (row & 7);
      aq[kss] = *(const bf16x8*)&lds_q[row * 64 + slot * 8];
    }
  }

  float mst[4], lst[4];
#pragma unroll
  for (int r = 0; r < 4; ++r) { mst[r] = -3.0e38f; lst[r] = 0.f; }
  const int lr0 = wave * 16 + g * 4;

  // ---------- PASS 1: row max + sum ----------
  for (int t0 = 0; t0 < S_; t0 += 64) {
    __syncthreads();
#pragma unroll
    for (int j = 0; j < 2; ++j) {
      int c = wave * 2 + j;
      int row = c * 8 + r8;
      int slot = s8 ^ (row & 7);
      gload_lds16(ksb + (size_t)(t0 + row) * 64 + slot * 8, &lds_k[c * 512]);
    }
    __syncthreads();
    float bl[4][4];
#pragma unroll
    for (int ct = 0; ct < 4; ++ct) {
      f32x4 acc = {0.f, 0.f, 0.f, 0.f};
#pragma unroll
      for (int kss = 0; kss < 2; ++kss) {
        int krow = ct * 16 + l4;
        int slot = (kss * 4 + g) ^ (krow & 7);
        bf16x8 bk_ = *(const bf16x8*)&lds_k[krow * 64 + slot * 8];
        acc = mfma_bf16(aq[kss], bk_, acc);
      }
      int t_ = t0 + ct * 16 + l4;
#pragma unroll
      for (int r = 0; r < 4; ++r) {
        float sc = acc[r] * 0.125f;
        int mv = maskb[(size_t)(lr0 + r) * S_ + t_];
        float pr = prib[(size_t)(lr0 + r) * S_ + t_];
        float z = __builtin_amdgcn_rcpf(1.f + __expf(-(sc + pr)));
        float blv = pr + z * (sc - pr);
        bl[ct][r] = mv ? -1.0e9f : blv;
      }
    }
#pragma unroll
    for (int r = 0; r < 4; ++r) {
      float tmax = fmaxf(fmaxf(bl[0][r], bl[1][r]), fmaxf(bl[2][r], bl[3][r]));
      tmax = fmaxf(tmax, __shfl_xor(tmax, 1));
      tmax = fmaxf(tmax, __shfl_xor(tmax, 2));
      tmax = fmaxf(tmax, __shfl_xor(tmax, 4));
      tmax = fmaxf(tmax, __shfl_xor(tmax, 8));
      float mnew = fmaxf(mst[r], tmax);
      float p = __expf(bl[0][r] - mnew) + __expf(bl[1][r] - mnew) +
                __expf(bl[2][r] - mnew) + __expf(bl[3][r] - mnew);
      p += __shfl_xor(p, 1);
      p += __shfl_xor(p, 2);
      p += __shfl_xor(p, 4);
      p += __shfl_xor(p, 8);
      lst[r] = lst[r] * __expf(mst[r] - mnew) + p;
      mst[r] = mnew;
    }
  }

  float invl[4];
#pragma unroll
  for (int r = 0; r < 4; ++r) invl[r] = 1.f / lst[r];

  f32x4 acc2[4];
#pragma unroll
  for (int ni = 0; ni < 4; ++ni) acc2[ni] = {0.f, 0.f, 0.f, 0.f};

  // ---------- PASS 2: recompute, write attn, PV ----------
  for (int t0 = 0; t0 < S_; t0 += 64) {
    __syncthreads();
#pragma unroll
    for (int j = 0; j < 2; ++j) {
      int c = wave * 2 + j;
      int row = c * 8 + r8;
      int slot = s8 ^ (row & 7);
      gload_lds16(ksb + (size_t)(t0 + row) * 64 + slot * 8, &lds_k[c * 512]);
      gload_lds16(vtb + (size_t)row * S_ + t0 + slot * 8, &lds_v[c * 512]);
    }
    __syncthreads();
#pragma unroll
    for (int ct = 0; ct < 4; ++ct) {
      f32x4 acc = {0.f, 0.f, 0.f, 0.f};
#pragma unroll
      for (int kss = 0; kss < 2; ++kss) {
        int krow = ct * 16 + l4;
        int slot = (kss * 4 + g) ^ (krow & 7);
        bf16x8 bk_ = *(const bf16x8*)&lds_k[krow * 64 + slot * 8];
        acc = mfma_bf16(aq[kss], bk_, acc);
      }
      int t_ = t0 + ct * 16 + l4;
#pragma unroll
      for (int r = 0; r < 4; ++r) {
        float sc = acc[r] * 0.125f;
        int mv = maskb[(size_t)(lr0 + r) * S_ + t_];
        float pr = prib[(size_t)(lr0 + r) * S_ + t_];
        float z = __builtin_amdgcn_rcpf(1.f + __expf(-(sc + pr)));
        float blv = pr + z * (sc - pr);
        blv = mv ? -1.0e9f : blv;
        float a = __expf(blv - mst[r]) * invl[r];
        attb[(size_t)(lr0 + r) * (H_ * S_) + t_] = a;
        int prow = g * 4 + r;
        int col = ct * 16 + l4;
        int sl = (col >> 3) ^ (prow & 7);
        lds_p[wave][prow * 64 + sl * 8 + (col & 7)] = f2bf(a);
      }
    }
    bf16x8 pa[2];
    {
      int prow = l4;
#pragma unroll
      for (int kss = 0; kss < 2; ++kss) {
        int slot = (kss * 4 + g) ^ (prow & 7);
        pa[kss] = *(const bf16x8*)&lds_p[wave][prow * 64 + slot * 8];
      }
    }
#pragma unroll
    for (int ni = 0; ni < 4; ++ni) {
#pragma unroll
      for (int kss = 0; kss < 2; ++kss) {
        int vrow = ni * 16 + l4;
        int slot = (kss * 4 + g) ^ (vrow & 7);
        bf16x8 bv_ = *(const bf16x8*)&lds_v[vrow * 64 + slot * 8];
        acc2[ni] = mfma_bf16(pa[kss], bv_, acc2[ni]);
      }
    }
  }

#pragma unroll
  for (int ni = 0; ni < 4; ++ni)
#pragma unroll
    for (int r = 0; r < 4; ++r)
      headb[(size_t)(lr0 + r) * DK_ + ni * 16 + l4] = acc2[ni][r];
}

// ---------------- launch ----------------

extern "C" void kernel_launch(void* const* d_in, const int* in_sizes, int n_in,
                              void* d_out, int out_size, void* d_ws, size_t ws_size,
                              hipStream_t stream) {
  (void)in_sizes; (void)n_in; (void)out_size; (void)ws_size;
  const float* q     = (const float*)d_in[0];
  const float* k     = (const float*)d_in[1];
  const float* v     = (const float*)d_in[2];
  const int*   mask  = (const int*)d_in[3];
  const float* prior = (const float*)d_in[4];
  const float* Wq    = (const float*)d_in[5];
  const float* bq    = (const float*)d_in[6];
  const float* Wk    = (const float*)d_in[7];
  const float* bk    = (const float*)d_in[8];
  const float* Wv    = (const float*)d_in[9];
  const float* bv    = (const float*)d_in[10];
  const float* Wh    = (const float*)d_in[11];

  float* out  = (float*)d_out;
  float* attn = out + (size_t)4096 * 1024;

  char* ws = (char*)d_ws;
  unsigned short* q_bf  = (unsigned short*)(ws + 0);
  unsigned short* k_bf  = (unsigned short*)(ws + 8388608);
  unsigned short* v_bf  = (unsigned short*)(ws + 16777216);
  unsigned short* WqT   = (unsigned short*)(ws + 25165824);
  unsigned short* WkT   = (unsigned short*)(ws + 27262976);
  unsigned short* WvT   = (unsigned short*)(ws + 29360128);
  unsigned short* WhT   = (unsigned short*)(ws + 29491200);
  unsigned short* qs_bf = (unsigned short*)(ws + 29622272);
  unsigned short* ks_bf = (unsigned short*)(ws + 38010880);
  unsigned short* vsT   = (unsigned short*)(ws + 46399488);
  // dead-buffer reuse after projections:
  float*          heads = (float*)(ws + 0);           // over q_bf+k_bf (16 MB)
  unsigned short* hbar  = (unsigned short*)(ws + 16777216);  // over v_bf

  f32_to_bf16_vec<<<4096, 256, 0, stream>>>(q, q_bf, 1048576);
  f32_to_bf16_vec<<<4096, 256, 0, stream>>>(k, k_bf, 1048576);
  f32_to_bf16_vec<<<4096, 256, 0, stream>>>(v, v_bf, 1048576);
  pack_wqk<<<4096, 256, 0, stream>>>(Wq, WqT);
  pack_wqk<<<4096, 256, 0, stream>>>(Wk, WkT);
  pack_wv<<<256, 256, 0, stream>>>(Wv, WvT);
  pack_wh<<<256, 256, 0, stream>>>(Wh, WhT);

  gemm_bt<128, 0><<<dim3(32, 8), 256, 0, stream>>>(q_bf, WqT, bq, qs_bf, 4096, 1024, 1024);
  gemm_bt<128, 0><<<dim3(32, 8), 256, 0, stream>>>(k_bf, WkT, bk, ks_bf, 4096, 1024, 1024);
  gemm_bt<64, 1><<<dim3(32, 1), 256, 0, stream>>>(v_bf, WvT, bv, vsT, 4096, 64, 1024);

  attn_kernel<<<1024, 256, 0, stream>>>(qs_bf, ks_bf, vsT, mask, prior, attn, heads);

  mean_heads<<<1024, 256, 0, stream>>>(heads, hbar);
  gemm_bt<128, 2><<<dim3(32, 8), 256, 0, stream>>>(hbar, WhT, nullptr, out, 4096, 1024, 64);
}

// Round 2
// 554.275 us; speedup vs baseline: 1.0497x; 1.0497x over previous
//
#include <hip/hip_runtime.h>

#define DEV __device__ __forceinline__

using f32x4  = __attribute__((ext_vector_type(4))) float;
using bf16x8 = __attribute__((ext_vector_type(8))) __bf16;
using u16x4  = __attribute__((ext_vector_type(4))) unsigned short;

constexpr int S_ = 2048, D_ = 1024, H_ = 16, DK_ = 64;

DEV unsigned short f2bf(float x) {
  unsigned int u = __float_as_uint(x);
  u += 0x7fffu + ((u >> 16) & 1u);
  return (unsigned short)(u >> 16);
}

DEV void gload_lds16(const void* g, void* l) {
  __builtin_amdgcn_global_load_lds(
      (__attribute__((address_space(1))) void*)g,
      (__attribute__((address_space(3))) void*)l, 16, 0, 0);
}

DEV f32x4 mfma_bf16(bf16x8 a, bf16x8 b, f32x4 c) {
  return __builtin_amdgcn_mfma_f32_16x16x32_bf16(a, b, c, 0, 0, 0);
}

// ---------------- elementwise converters / packers ----------------

__global__ __launch_bounds__(256) void f32_to_bf16_vec(
    const float* __restrict__ s, unsigned short* __restrict__ d, int n4) {
  int i = blockIdx.x * 256 + threadIdx.x;
  if (i >= n4) return;
  f32x4 v = *(const f32x4*)(s + (size_t)i * 4);
  u16x4 o;
  o[0] = f2bf(v[0]); o[1] = f2bf(v[1]); o[2] = f2bf(v[2]); o[3] = f2bf(v[3]);
  *(u16x4*)(d + (size_t)i * 4) = o;
}

// pm = mask ? -1e9 : prior   (f32)
__global__ __launch_bounds__(256) void make_pm(
    const int* __restrict__ mask, const float* __restrict__ prior,
    float* __restrict__ pm, int n4) {
  int i = blockIdx.x * 256 + threadIdx.x;
  if (i >= n4) return;
  const int* m = mask + (size_t)i * 4;
  f32x4 p = *(const f32x4*)(prior + (size_t)i * 4);
  f32x4 o;
#pragma unroll
  for (int j = 0; j < 4; ++j) o[j] = m[j] ? -1.0e9f : p[j];
  *(f32x4*)(pm + (size_t)i * 4) = o;
}

// WT[n][d] = W[h][d][kk], n = h*64+kk   (Wq / Wk, total 1024*1024)
__global__ __launch_bounds__(256) void pack_wqk(
    const float* __restrict__ W, unsigned short* __restrict__ WT) {
  int i = blockIdx.x * 256 + threadIdx.x;
  int d = i & 1023, n = i >> 10;
  int hh = n >> 6, kk = n & 63;
  WT[i] = f2bf(W[((size_t)hh * 1024 + d) * 64 + kk]);
}

// WvT[kk][d] = Wv[d][kk]   (64*1024)
__global__ __launch_bounds__(256) void pack_wv(
    const float* __restrict__ W, unsigned short* __restrict__ WT) {
  int i = blockIdx.x * 256 + threadIdx.x;
  int d = i & 1023, kk = i >> 10;
  WT[i] = f2bf(W[(size_t)d * 64 + kk]);
}

// WhT[n][k] = Wh[k][n]   (1024*64)
__global__ __launch_bounds__(256) void pack_wh(
    const float* __restrict__ W, unsigned short* __restrict__ WT) {
  int i = blockIdx.x * 256 + threadIdx.x;
  int k = i & 63, n = i >> 6;
  WT[i] = f2bf(W[(size_t)k * 1024 + n]);
}

__global__ __launch_bounds__(256) void mean_heads(
    const float* __restrict__ heads, unsigned short* __restrict__ hbar) {
  int i = blockIdx.x * 256 + threadIdx.x;  // 4096*64
  int kk = i & 63, m = i >> 6;
  int b = m >> 11, s = m & 2047;
  float acc = 0.f;
#pragma unroll
  for (int hh = 0; hh < 16; ++hh)
    acc += heads[(((size_t)b * 16 + hh) * 2048 + s) * 64 + kk];
  hbar[i] = f2bf(acc * 0.0625f);
}

// ---------------- bf16 MFMA GEMM, C = A * BT^T (+bias), custom epilogues ----
// MODE 0: bf16 out at [b][h][s][kk]  (m=b*2048+s, n=h*64+kk)  (qs/ks)
// MODE 1: bf16 out at [b][n][t]      (m=b*2048+t, N=64)       (vsT)
// MODE 2: f32 out at [m][n]          (out projection, no bias)

template <int BN, int MODE>
__global__ __launch_bounds__(256) void gemm_bt(
    const unsigned short* __restrict__ A, const unsigned short* __restrict__ BT,
    const float* __restrict__ bias, void* __restrict__ outp, int M, int N, int K) {
  constexpr int BM = 128, BK = 64;
  constexpr int NWC = BN / 64;     // waves along N
  constexpr int NWR = 4 / NWC;     // waves along M
  constexpr int WTM = BM / NWR;    // rows per wave
  constexpr int MI = WTM / 16;
  constexpr int NI = 4;
  __shared__ unsigned short ldsA[BM * BK];
  __shared__ unsigned short ldsB[BN * BK];
  const int tid = threadIdx.x;
  const int wave = tid >> 6, lane = tid & 63;
  const int g = lane >> 4, l4 = lane & 15;
  const int m0 = blockIdx.x * BM, n0 = blockIdx.y * BN;
  const int wr = wave / NWC, wc = wave % NWC;
  const int r8 = lane >> 3, s8 = lane & 7;
  f32x4 acc[MI][NI];
#pragma unroll
  for (int mi = 0; mi < MI; ++mi)
#pragma unroll
    for (int ni = 0; ni < NI; ++ni) acc[mi][ni] = {0.f, 0.f, 0.f, 0.f};

  for (int k0 = 0; k0 < K; k0 += BK) {
    __syncthreads();
#pragma unroll
    for (int j = 0; j < 4; ++j) {  // A: 16 chunks of 1 KiB
      int c = wave * 4 + j;
      int row = c * 8 + r8;
      int slot = s8 ^ (row & 7);
      gload_lds16(A + (size_t)(m0 + row) * K + k0 + slot * 8, &ldsA[c * 512]);
    }
    constexpr int BCH = BN * BK / 512;  // 16 or 8 chunks
#pragma unroll
    for (int j = 0; j < BCH / 4; ++j) {
      int c = wave * (BCH / 4) + j;
      int row = c * 8 + r8;
      int slot = s8 ^ (row & 7);
      gload_lds16(BT + (size_t)(n0 + row) * K + k0 + slot * 8, &ldsB[c * 512]);
    }
    __syncthreads();
    bf16x8 af[MI][2], bfr[NI][2];
#pragma unroll
    for (int mi = 0; mi < MI; ++mi)
#pragma unroll
      for (int kss = 0; kss < 2; ++kss) {
        int row = wr * WTM + mi * 16 + l4;
        int slot = (kss * 4 + g) ^ (row & 7);
        af[mi][kss] = *(const bf16x8*)&ldsA[row * 64 + slot * 8];
      }
#pragma unroll
    for (int ni = 0; ni < NI; ++ni)
#pragma unroll
      for (int kss = 0; kss < 2; ++kss) {
        int row = wc * 64 + ni * 16 + l4;
        int slot = (kss * 4 + g) ^ (row & 7);
        bfr[ni][kss] = *(const bf16x8*)&ldsB[row * 64 + slot * 8];
      }
#pragma unroll
    for (int mi = 0; mi < MI; ++mi)
#pragma unroll
      for (int ni = 0; ni < NI; ++ni)
#pragma unroll
        for (int kss = 0; kss < 2; ++kss)
          acc[mi][ni] = mfma_bf16(af[mi][kss], bfr[ni][kss], acc[mi][ni]);
  }

#pragma unroll
  for (int mi = 0; mi < MI; ++mi)
#pragma unroll
    for (int ni = 0; ni < NI; ++ni)
#pragma unroll
      for (int r = 0; r < 4; ++r) {
        int m = m0 + wr * WTM + mi * 16 + g * 4 + r;
        int n = n0 + wc * 64 + ni * 16 + l4;
        float c = acc[mi][ni][r];
        if constexpr (MODE != 2) c += bias[n];
        if constexpr (MODE == 0) {
          int b = m >> 11, s = m & 2047, hh = n >> 6, kk = n & 63;
          ((unsigned short*)outp)[(((size_t)b * 16 + hh) * 2048 + s) * 64 + kk] = f2bf(c);
        } else if constexpr (MODE == 1) {
          int b = m >> 11, t = m & 2047;
          ((unsigned short*)outp)[((size_t)b * 64 + n) * 2048 + t] = f2bf(c);
        } else {
          ((float*)outp)[(size_t)m * N + n] = c;
        }
      }
}

// ---------------- fused attention ----------------
// 1 wave per block, 16 q-rows. NO barriers: K/V/Q fragments loaded directly
// from global (L2-resident); only per-wave P-transpose LDS (2 KB).
// Two passes over T: pass1 online max+sum, pass2 recompute + attn write + PV.

__global__ __launch_bounds__(64, 4) void attn_kernel(
    const unsigned short* __restrict__ qs, const unsigned short* __restrict__ ks,
    const unsigned short* __restrict__ vsT, const float* __restrict__ pm,
    float* __restrict__ attn_out, float* __restrict__ heads) {
  __shared__ unsigned short lds_p[16 * 64];

  const int lane = threadIdx.x & 63;
  const int g = lane >> 4, l4 = lane & 15;
  // bijective XCD swizzle: 4096 blocks, XCD x gets contiguous 512-chunk
  const int wg = blockIdx.x;
  const int swz = (wg & 7) * 512 + (wg >> 3);
  const int sblk = swz & 127, bh = swz >> 7;
  const int b = bh >> 4, h = bh & 15;

  const size_t bhS = (size_t)bh * S_;
  const unsigned short* qsb = qs + (bhS + sblk * 16) * DK_;
  const unsigned short* ksb = ks + bhS * DK_;
  const unsigned short* vtb = vsT + (size_t)b * DK_ * S_;
  const float* pmb = pm + ((size_t)b * S_ + sblk * 16) * S_;
  float* attb = attn_out + (((size_t)b * S_ + sblk * 16) * H_ + h) * S_;
  float* headb = heads + (bhS + sblk * 16) * DK_;

  // Q fragments (A operand): row = l4, k-block = (kss*4+g)*8
  bf16x8 aq[2];
#pragma unroll
  for (int kss = 0; kss < 2; ++kss)
    aq[kss] = *(const bf16x8*)(qsb + (size_t)l4 * DK_ + (kss * 4 + g) * 8);

  const int lr0 = g * 4;
  float mst[4], lst[4];
#pragma unroll
  for (int r = 0; r < 4; ++r) { mst[r] = -3.0e38f; lst[r] = 0.f; }

  // ---------- PASS 1: row max + sum ----------
  for (int t0 = 0; t0 < S_; t0 += 64) {
    float pmv[4][4];
#pragma unroll
    for (int ct = 0; ct < 4; ++ct)
#pragma unroll
      for (int r = 0; r < 4; ++r)
        pmv[ct][r] = pmb[(size_t)(lr0 + r) * S_ + t0 + ct * 16 + l4];
    float bl[4][4];
#pragma unroll
    for (int ct = 0; ct < 4; ++ct) {
      f32x4 acc = {0.f, 0.f, 0.f, 0.f};
#pragma unroll
      for (int kss = 0; kss < 2; ++kss) {
        bf16x8 bk_ = *(const bf16x8*)(ksb + (size_t)(t0 + ct * 16 + l4) * DK_ + (kss * 4 + g) * 8);
        acc = mfma_bf16(aq[kss], bk_, acc);
      }
#pragma unroll
      for (int r = 0; r < 4; ++r) {
        float pr = pmv[ct][r];
        float sc = acc[r] * 0.125f;
        float z = __builtin_amdgcn_rcpf(1.f + __expf(-(sc + pr)));
        bl[ct][r] = pr + z * (sc - pr);
      }
    }
#pragma unroll
    for (int r = 0; r < 4; ++r) {
      float tmax = fmaxf(fmaxf(bl[0][r], bl[1][r]), fmaxf(bl[2][r], bl[3][r]));
      tmax = fmaxf(tmax, __shfl_xor(tmax, 1));
      tmax = fmaxf(tmax, __shfl_xor(tmax, 2));
      tmax = fmaxf(tmax, __shfl_xor(tmax, 4));
      tmax = fmaxf(tmax, __shfl_xor(tmax, 8));
      float mnew = fmaxf(mst[r], tmax);
      float p = __expf(bl[0][r] - mnew) + __expf(bl[1][r] - mnew) +
                __expf(bl[2][r] - mnew) + __expf(bl[3][r] - mnew);
      p += __shfl_xor(p, 1);
      p += __shfl_xor(p, 2);
      p += __shfl_xor(p, 4);
      p += __shfl_xor(p, 8);
      lst[r] = lst[r] * __expf(mst[r] - mnew) + p;
      mst[r] = mnew;
    }
  }

  float invl[4];
#pragma unroll
  for (int r = 0; r < 4; ++r) invl[r] = 1.f / lst[r];

  f32x4 acc2[4];
#pragma unroll
  for (int ni = 0; ni < 4; ++ni) acc2[ni] = {0.f, 0.f, 0.f, 0.f};

  // ---------- PASS 2: recompute, write attn, PV ----------
  for (int t0 = 0; t0 < S_; t0 += 64) {
    float pmv[4][4];
#pragma unroll
    for (int ct = 0; ct < 4; ++ct)
#pragma unroll
      for (int r = 0; r < 4; ++r)
        pmv[ct][r] = pmb[(size_t)(lr0 + r) * S_ + t0 + ct * 16 + l4];
#pragma unroll
    for (int ct = 0; ct < 4; ++ct) {
      f32x4 acc = {0.f, 0.f, 0.f, 0.f};
#pragma unroll
      for (int kss = 0; kss < 2; ++kss) {
        bf16x8 bk_ = *(const bf16x8*)(ksb + (size_t)(t0 + ct * 16 + l4) * DK_ + (kss * 4 + g) * 8);
        acc = mfma_bf16(aq[kss], bk_, acc);
      }
      int t_ = t0 + ct * 16 + l4;
#pragma unroll
      for (int r = 0; r < 4; ++r) {
        float pr = pmv[ct][r];
        float sc = acc[r] * 0.125f;
        float z = __builtin_amdgcn_rcpf(1.f + __expf(-(sc + pr)));
        float blv = pr + z * (sc - pr);
        float a = __expf(blv - mst[r]) * invl[r];
        attb[(size_t)(lr0 + r) * (H_ * S_) + t_] = a;
        int prow = lr0 + r;
        int col = ct * 16 + l4;
        int sl = (col >> 3) ^ (prow & 7);
        lds_p[prow * 64 + sl * 8 + (col & 7)] = f2bf(a);
      }
    }
    bf16x8 pa[2];
    {
      int prow = l4;
#pragma unroll
      for (int kss = 0; kss < 2; ++kss) {
        int slot = (kss * 4 + g) ^ (prow & 7);
        pa[kss] = *(const bf16x8*)&lds_p[prow * 64 + slot * 8];
      }
    }
#pragma unroll
    for (int ni = 0; ni < 4; ++ni) {
#pragma unroll
      for (int kss = 0; kss < 2; ++kss) {
        bf16x8 bv_ = *(const bf16x8*)(vtb + (size_t)(ni * 16 + l4) * S_ + t0 + (kss * 4 + g) * 8);
        acc2[ni] = mfma_bf16(pa[kss], bv_, acc2[ni]);
      }
    }
  }

#pragma unroll
  for (int ni = 0; ni < 4; ++ni)
#pragma unroll
    for (int r = 0; r < 4; ++r)
      headb[(size_t)(lr0 + r) * DK_ + ni * 16 + l4] = acc2[ni][r];
}

// ---------------- launch ----------------

extern "C" void kernel_launch(void* const* d_in, const int* in_sizes, int n_in,
                              void* d_out, int out_size, void* d_ws, size_t ws_size,
                              hipStream_t stream) {
  (void)in_sizes; (void)n_in; (void)out_size; (void)ws_size;
  const float* q     = (const float*)d_in[0];
  const float* k     = (const float*)d_in[1];
  const float* v     = (const float*)d_in[2];
  const int*   mask  = (const int*)d_in[3];
  const float* prior = (const float*)d_in[4];
  const float* Wq    = (const float*)d_in[5];
  const float* bq    = (const float*)d_in[6];
  const float* Wk    = (const float*)d_in[7];
  const float* bk    = (const float*)d_in[8];
  const float* Wv    = (const float*)d_in[9];
  const float* bv    = (const float*)d_in[10];
  const float* Wh    = (const float*)d_in[11];

  float* out  = (float*)d_out;
  float* attn = out + (size_t)4096 * 1024;

  char* ws = (char*)d_ws;
  // region A (0..33.5MB): q_bf/k_bf/v_bf during projections, then pm
  unsigned short* q_bf  = (unsigned short*)(ws + 0);
  unsigned short* k_bf  = (unsigned short*)(ws + 8388608);
  unsigned short* v_bf  = (unsigned short*)(ws + 16777216);
  float*          pm    = (float*)(ws + 0);            // 33554432 B, after gemms
  unsigned short* WqT   = (unsigned short*)(ws + 33554432);
  unsigned short* WkT   = (unsigned short*)(ws + 35651584);
  unsigned short* WvT   = (unsigned short*)(ws + 37748736);
  unsigned short* WhT   = (unsigned short*)(ws + 37879808);
  unsigned short* qs_bf = (unsigned short*)(ws + 38010880);
  unsigned short* ks_bf = (unsigned short*)(ws + 46399488);
  unsigned short* vsT   = (unsigned short*)(ws + 54788096);
  float*          heads = (float*)(ws + 55312384);     // 16777216 B
  unsigned short* hbar  = (unsigned short*)(ws + 72089600);

  f32_to_bf16_vec<<<4096, 256, 0, stream>>>(q, q_bf, 1048576);
  f32_to_bf16_vec<<<4096, 256, 0, stream>>>(k, k_bf, 1048576);
  f32_to_bf16_vec<<<4096, 256, 0, stream>>>(v, v_bf, 1048576);
  pack_wqk<<<4096, 256, 0, stream>>>(Wq, WqT);
  pack_wqk<<<4096, 256, 0, stream>>>(Wk, WkT);
  pack_wv<<<256, 256, 0, stream>>>(Wv, WvT);
  pack_wh<<<256, 256, 0, stream>>>(Wh, WhT);

  gemm_bt<128, 0><<<dim3(32, 8), 256, 0, stream>>>(q_bf, WqT, bq, qs_bf, 4096, 1024, 1024);
  gemm_bt<128, 0><<<dim3(32, 8), 256, 0, stream>>>(k_bf, WkT, bk, ks_bf, 4096, 1024, 1024);
  gemm_bt<64, 1><<<dim3(32, 1), 256, 0, stream>>>(v_bf, WvT, bv, vsT, 4096, 64, 1024);

  make_pm<<<8192, 256, 0, stream>>>(mask, prior, pm, 2097152);

  attn_kernel<<<4096, 64, 0, stream>>>(qs_bf, ks_bf, vsT, pm, attn, heads);

  mean_heads<<<1024, 256, 0, stream>>>(heads, hbar);
  gemm_bt<128, 2><<<dim3(32, 8), 256, 0, stream>>>(hbar, WhT, nullptr, out, 4096, 1024, 64);
}